// Round 3
// baseline (1486.166 us; speedup 1.0000x reference)
//
#include <hip/hip_runtime.h>
#include <hip/hip_bf16.h>
#include <cstdint>

// Problem dims
#define DD 1024
#define LIN 1024
#define LP 511
#define LPAD 512
#define NBATCH 32
#define KCB 2048
#define BN_EPS 1e-5f

// Output layout (floats): q_st [32,1024,511], ids [32,511], commitment, codebook_loss
#define OUT_IDS 16744448u
#define OUT_LOSS 16760800u

// Workspace layout (float offsets). Region X = [WS_UNI, WS_AUX) is
// phase-multiplexed: phase0 conv1 operands; phase2 t2 + r/z planes + small planes.
#define WS_H1 0
#define WS_UNI 16777216
// phase0 (conv1):
#define WS_XH  (WS_UNI)                    // [2][32][512][1024] ushort (+512 f pad)
#define WS_XL  (WS_UNI + 16777728)
#define WS_WTH (WS_UNI + 33555456)         // [4][1024][1024] ushort
#define WS_WTL (WS_UNI + 35652608)
// phase2 (after conv1 done):
#define WS_T2  (WS_UNI)                    // fp32 [32][1024][512]
#define WS_RH  (WS_UNI + 16777216)         // [32][512][1024] ushort
#define WS_RL  (WS_UNI + 25165824)
#define WS_ZH  WS_RH                       // reuse after conv2 done
#define WS_ZL  WS_RL
#define WS_W2H (WS_UNI + 33554432)         // [1024][1024] ushort
#define WS_W2L (WS_UNI + 34078720)
#define WS_CBH (WS_UNI + 34603008)         // [2048][1024] ushort
#define WS_CBL (WS_UNI + 35651584)
#define WS_AUX (WS_UNI + 37749760)
#define WS_A1 (WS_AUX + 0)
#define WS_B1 (WS_AUX + 1024)
#define WS_A2 (WS_AUX + 2048)
#define WS_B2 (WS_AUX + 3072)
#define WS_E2 (WS_AUX + 4096)
#define WS_SLOTS (WS_AUX + 6144)
#define WS_LOSS (WS_AUX + 6144 + 32704)

typedef __attribute__((ext_vector_type(8))) short bf16x8;
typedef __attribute__((ext_vector_type(4))) float f32x4;
typedef __attribute__((ext_vector_type(16))) float f32x16;
typedef __attribute__((ext_vector_type(4))) unsigned short ushort4v;

__device__ __forceinline__ void async_cp16(const void* gsrc, void* ldst) {
  __builtin_amdgcn_global_load_lds(
      (const __attribute__((address_space(1))) unsigned int*)gsrc,
      (__attribute__((address_space(3))) unsigned int*)ldst, 16, 0, 0);
}

__device__ __forceinline__ void bf16split(float v, unsigned short& hi, unsigned short& lo) {
  __hip_bfloat16 h = __float2bfloat16(v);
  float hf = __bfloat162float(h);
  __hip_bfloat16 l = __float2bfloat16(v - hf);
  hi = *(unsigned short*)&h;
  lo = *(unsigned short*)&l;
}

__device__ inline float blockReduce256(float v, float* sb) {
#pragma unroll
  for (int off = 32; off > 0; off >>= 1) v += __shfl_down(v, off);
  __syncthreads();
  if ((threadIdx.x & 63) == 0) sb[threadIdx.x >> 6] = v;
  __syncthreads();
  return sb[0] + sb[1] + sb[2] + sb[3];
}

#define VMCNT(n) asm volatile("s_waitcnt vmcnt(" #n ")" ::: "memory")

// ---------------------------------------------------------------------------
// 256x256 tile MFMA core (32x32x16), 512 threads = 8 waves (2M x 4N),
// wave tile 128x64 = 4 mt x 2 nt tiles of 32x32.
// LDS: 4 planes per K=32 chunk: Ah(0), Al(8192), Bh(16384), Bl(24576) hw
// offsets; 256 rows x 32 hw per plane; double-buffered (stride 32768 hw).
// Swizzle: 16B slot s within each 64B row stored at s ^ ((row>>1)&3), applied
// by pre-swizzling the GLOBAL source of global_load_lds; same XOR on reads.
//
// DMA slots (1KB each): 0,1:Bh 2,3:Bl (rows split by wid); 4+j: A rows
// [j*32,+32) & [128+j*32,+32) both planes (split by wid).
//
// Phase-ahead pipeline (fragments ds_read one barrier-phase before use):
//  P0(c): VMCNT(4) bar | read A0kh1,Bkh1,A1kh0 | DMA A(c+1) | MFMA A0xB
//  P1(c): VMCNT(2) bar | read A1kh1,B(c+1)kh0,A0(c+1)kh0 | DMA B(c+2) | MFMA A1xB
// Queue at P0 entry: [A(c)x4, B(c+1)x4] -> VMCNT(4) completes A(c).
// Queue at P1 entry: [B(c+1)x4, A(c+1)x4] -> VMCNT(2) completes B(c+1)+A(c+1)[4,5].
template <typename SF>
__device__ __forceinline__ void stage_slot(const SF& sf, int c, int slot,
                                           unsigned short* smbase, int wid,
                                           int lane) {
  int plane, r0;
  if (slot < 4) {
    plane = 2 + (slot >> 1);
    r0 = ((slot & 1) << 7) + (wid << 4);
  } else {
    plane = wid & 1;
    r0 = (((wid >> 1) & 1) << 7) + ((slot - 4) << 5) + ((wid >> 2) << 4);
  }
  const unsigned short* g = sf(c, plane) + (size_t)(r0 + (lane >> 2)) * 1024 +
                            (((lane & 3) ^ ((lane >> 3) & 3)) << 3);
  unsigned short* d = smbase + plane * 8192 + r0 * 32;  // HW adds lane*16B
  async_cp16(g, d);
}

template <int PH>
__device__ __forceinline__ void mfma_half(f32x16 (&acc)[4][2],
                                          const bf16x8 (&ah)[2],
                                          const bf16x8 (&al)[2],
                                          const bf16x8 (&bh)[2],
                                          const bf16x8 (&bl)[2]) {
#pragma unroll
  for (int t = 0; t < 3; ++t)
#pragma unroll
    for (int mi = 0; mi < 2; ++mi)
#pragma unroll
      for (int nt = 0; nt < 2; ++nt) {
        const bf16x8 af = (t == 2) ? al[mi] : ah[mi];
        const bf16x8 bb = (t == 1) ? bl[nt] : bh[nt];
        acc[PH * 2 + mi][nt] = __builtin_amdgcn_mfma_f32_32x32x16_bf16(
            af, bb, acc[PH * 2 + mi][nt], 0, 0, 0);
      }
}

#define FRAG(BASE, ROW, SIDX) \
  (*(const bf16x8*)((BASE) + (ROW) * 32 + (((SIDX) ^ sig) << 3)))

// One chunk: PP = parity literal (0/1); NX1 = (c+1<nkc); NX2 = (c+2<nkc).
#define CHUNK_BODY(CIDX, PP, NX1, NX2)                                        \
  {                                                                           \
    const int c__ = (CIDX);                                                   \
    unsigned short* bufc = sm + ((PP) << 15);                                 \
    unsigned short* bufn = sm + (((PP) ^ 1) << 15);                           \
    const unsigned short* As = bufc;                                          \
    const unsigned short* Als = bufc + 8192;                                  \
    const unsigned short* Bs = bufc + 16384;                                  \
    const unsigned short* Bls = bufc + 24576;                                 \
    const unsigned short* Asn = bufn;                                         \
    const unsigned short* Alsn = bufn + 8192;                                 \
    const unsigned short* Bsn = bufn + 16384;                                 \
    const unsigned short* Blsn = bufn + 24576;                                \
    /* ---- P0 ---- */                                                        \
    if (NX1) { VMCNT(4); } else { VMCNT(0); }                                 \
    __builtin_amdgcn_s_barrier();                                             \
    __builtin_amdgcn_sched_barrier(0);                                        \
    _Pragma("unroll") for (int mi = 0; mi < 2; ++mi) {                        \
      const int r = arowb + mi * 32;                                          \
      a0h[1][mi] = FRAG(As, r, 2 + khalf);                                    \
      a0l[1][mi] = FRAG(Als, r, 2 + khalf);                                   \
    }                                                                         \
    _Pragma("unroll") for (int nt = 0; nt < 2; ++nt) {                        \
      const int r = browb + nt * 32;                                          \
      bh1[nt] = FRAG(Bs, r, 2 + khalf);                                       \
      bl1[nt] = FRAG(Bls, r, 2 + khalf);                                      \
    }                                                                         \
    _Pragma("unroll") for (int mi = 0; mi < 2; ++mi) {                        \
      const int r = arowb + (2 + mi) * 32;                                    \
      a1h[0][mi] = FRAG(As, r, khalf);                                        \
      a1l[0][mi] = FRAG(Als, r, khalf);                                       \
    }                                                                         \
    if (NX1) {                                                                \
      _Pragma("unroll") for (int s = 4; s < 8; ++s)                           \
          stage_slot(sf, c__ + 1, s, bufn, wid, lane);                        \
    }                                                                         \
    __builtin_amdgcn_sched_barrier(0);                                        \
    __builtin_amdgcn_s_setprio(1);                                            \
    mfma_half<0>(acc, a0h[0], a0l[0], bh0[PP], bl0[PP]);                      \
    mfma_half<0>(acc, a0h[1], a0l[1], bh1, bl1);                              \
    __builtin_amdgcn_s_setprio(0);                                            \
    /* ---- P1 ---- */                                                        \
    if (NX1) { VMCNT(2); } else { VMCNT(0); }                                 \
    __builtin_amdgcn_s_barrier();                                             \
    __builtin_amdgcn_sched_barrier(0);                                        \
    _Pragma("unroll") for (int mi = 0; mi < 2; ++mi) {                        \
      const int r = arowb + (2 + mi) * 32;                                    \
      a1h[1][mi] = FRAG(As, r, 2 + khalf);                                    \
      a1l[1][mi] = FRAG(Als, r, 2 + khalf);                                   \
    }                                                                         \
    if (NX1) {                                                                \
      _Pragma("unroll") for (int nt = 0; nt < 2; ++nt) {                      \
        const int r = browb + nt * 32;                                        \
        bh0[(PP) ^ 1][nt] = FRAG(Bsn, r, khalf);                              \
        bl0[(PP) ^ 1][nt] = FRAG(Blsn, r, khalf);                             \
      }                                                                       \
      _Pragma("unroll") for (int mi = 0; mi < 2; ++mi) {                      \
        const int r = arowb + mi * 32;                                        \
        a0h[0][mi] = FRAG(Asn, r, khalf);                                     \
        a0l[0][mi] = FRAG(Alsn, r, khalf);                                    \
      }                                                                       \
    }                                                                         \
    if (NX2) {                                                                \
      _Pragma("unroll") for (int s = 0; s < 4; ++s)                           \
          stage_slot(sf, c__ + 2, s, bufc, wid, lane);                        \
    }                                                                         \
    __builtin_amdgcn_sched_barrier(0);                                        \
    __builtin_amdgcn_s_setprio(1);                                            \
    mfma_half<1>(acc, a1h[0], a1l[0], bh0[PP], bl0[PP]);                      \
    mfma_half<1>(acc, a1h[1], a1l[1], bh1, bl1);                              \
    __builtin_amdgcn_s_setprio(0);                                            \
  }

template <typename SF>
__device__ __forceinline__ void mfma256_core32(const SF& sf, unsigned short* sm,
                                               int nkc, f32x16 (&acc)[4][2]) {
  const int tid = threadIdx.x;
  const int wid = tid >> 6, lane = tid & 63;
  const int wm = wid >> 2, wn = wid & 3;
  const int lrow = lane & 31;
  const int khalf = lane >> 5;       // which 8-hw k-group this lane holds
  const int sig = (lane >> 1) & 3;   // row-swizzle sigma
  const int arowb = (wm << 7) + lrow;
  const int browb = (wn << 6) + lrow;

  bf16x8 a0h[2][2], a0l[2][2];  // [kh][mi] phase0 A
  bf16x8 a1h[2][2], a1l[2][2];  // [kh][mi] phase1 A
  bf16x8 bh0[2][2], bl0[2][2];  // [chunk-parity][nt] kh=0 B
  bf16x8 bh1[2], bl1[2];        // [nt] kh=1 B

  // prologue: DMA B(0),A(0) -> buf0; B(1) -> buf1
#pragma unroll
  for (int s = 0; s < 8; ++s) stage_slot(sf, 0, s, sm, wid, lane);
#pragma unroll
  for (int s = 0; s < 4; ++s) stage_slot(sf, 1, s, sm + 32768, wid, lane);
  VMCNT(4);
  __builtin_amdgcn_s_barrier();
  __builtin_amdgcn_sched_barrier(0);
  {
    const unsigned short* As = sm;
    const unsigned short* Als = sm + 8192;
    const unsigned short* Bs = sm + 16384;
    const unsigned short* Bls = sm + 24576;
#pragma unroll
    for (int nt = 0; nt < 2; ++nt) {
      const int r = browb + nt * 32;
      bh0[0][nt] = FRAG(Bs, r, khalf);
      bl0[0][nt] = FRAG(Bls, r, khalf);
    }
#pragma unroll
    for (int mi = 0; mi < 2; ++mi) {
      const int r = arowb + mi * 32;
      a0h[0][mi] = FRAG(As, r, khalf);
      a0l[0][mi] = FRAG(Als, r, khalf);
    }
  }

  for (int cc = 0; cc < nkc - 2; cc += 2) {
    CHUNK_BODY(cc, 0, true, true);
    CHUNK_BODY(cc + 1, 1, true, true);
  }
  CHUNK_BODY(nkc - 2, 0, true, false);
  CHUNK_BODY(nkc - 1, 1, false, false);
}

// ---------------------------------------------------------------------------
// split w1 [o][i][t] fp32 -> wth/wtl [t][o][i] bf16 hi/lo
__global__ __launch_bounds__(256) void split_w1_kernel(
    const float* __restrict__ w, unsigned short* __restrict__ wth,
    unsigned short* __restrict__ wtl) {
  int idx = blockIdx.x * 256 + threadIdx.x;
  int o = idx >> 10, i = idx & 1023;
  float4 v = *(const float4*)&w[(size_t)idx * 4];
  float vv[4] = {v.x, v.y, v.z, v.w};
#pragma unroll
  for (int t = 0; t < 4; ++t) {
    unsigned short hi, lo;
    bf16split(vv[t], hi, lo);
    size_t off = (((size_t)(t << 10) + o) << 10) + i;
    wth[off] = hi;
    wtl[off] = lo;
  }
}

// ---------------------------------------------------------------------------
// generic row-major split: src [rows][1024] fp32 -> dsth/dstl bf16 hi/lo
__global__ __launch_bounds__(256) void split_rows_kernel(
    const float* __restrict__ src, unsigned short* __restrict__ dsth,
    unsigned short* __restrict__ dstl) {
  size_t base = ((size_t)blockIdx.x * 256 + threadIdx.x) * 4;
  float4 v = *(const float4*)&src[base];
  float vv[4] = {v.x, v.y, v.z, v.w};
  ushort4v h, l;
#pragma unroll
  for (int j = 0; j < 4; ++j) {
    unsigned short hi, lo;
    bf16split(vv[j], hi, lo);
    h[j] = hi;
    l[j] = lo;
  }
  *(ushort4v*)&dsth[base] = h;
  *(ushort4v*)&dstl[base] = l;
}

// ---------------------------------------------------------------------------
// split/transpose x [n][i][l] fp32 -> xh/xl [P][n][l>>1][i] bf16 (P = l&1)
__global__ __launch_bounds__(256) void split_x_kernel(
    const float* __restrict__ x, unsigned short* __restrict__ xh,
    unsigned short* __restrict__ xl) {
  __shared__ float lsT[128 * 65];
  const int l0 = blockIdx.x * 128;
  const int i0 = blockIdx.y * 64;
  const int nB = blockIdx.z;
  const int tid = threadIdx.x;
#pragma unroll
  for (int p = 0; p < 8; ++p) {
    int flat = p * 256 + tid;
    int row = flat >> 5, col4 = (flat & 31) * 4;
    float4 v = *(const float4*)&x[((size_t)nB * DD + i0 + row) * LIN + l0 + col4];
    lsT[(col4 + 0) * 65 + row] = v.x;
    lsT[(col4 + 1) * 65 + row] = v.y;
    lsT[(col4 + 2) * 65 + row] = v.z;
    lsT[(col4 + 3) * 65 + row] = v.w;
  }
  __syncthreads();
  const int lo2 = (l0 >> 1);
#pragma unroll
  for (int p = 0; p < 16; ++p) {
    int cp = p * 4 + (tid >> 6);
    int il = tid & 63;
    float vE = lsT[(2 * cp) * 65 + il];
    float vO = lsT[(2 * cp + 1) * 65 + il];
    unsigned short hE, lE, hO, lO;
    bf16split(vE, hE, lE);
    bf16split(vO, hO, lO);
    size_t dE = (((size_t)(0 * 32 + nB) * 512) + lo2 + cp) * 1024 + i0 + il;
    size_t dO = (((size_t)(1 * 32 + nB) * 512) + lo2 + cp) * 1024 + i0 + il;
    xh[dE] = hE; xl[dE] = lE;
    xh[dO] = hO; xl[dO] = lO;
  }
}

// ---------------------------------------------------------------------------
// transpose + per-channel affine (+optional relu) + bf16 split:
// src [n][c][LPAD] fp32 -> dsth/dstl [n][LPAD][1024] bf16 hi/lo of (a*v+b)
__global__ __launch_bounds__(256) void trans_affine_split_kernel(
    const float* __restrict__ src, const float* __restrict__ a,
    const float* __restrict__ b, unsigned short* __restrict__ dsth,
    unsigned short* __restrict__ dstl, int do_relu) {
  __shared__ float lsT[128 * 65];
  const int l0 = blockIdx.x * 128;
  const int i0 = blockIdx.y * 64;
  const int nB = blockIdx.z;
  const int tid = threadIdx.x;
#pragma unroll
  for (int p = 0; p < 8; ++p) {
    int flat = p * 256 + tid;
    int row = flat >> 5, col4 = (flat & 31) * 4;
    float4 v = *(const float4*)&src[((size_t)nB * DD + i0 + row) * LPAD + l0 + col4];
    lsT[(col4 + 0) * 65 + row] = v.x;
    lsT[(col4 + 1) * 65 + row] = v.y;
    lsT[(col4 + 2) * 65 + row] = v.z;
    lsT[(col4 + 3) * 65 + row] = v.w;
  }
  __syncthreads();
  const int il = tid & 63;
  const float ac = a[i0 + il], bc = b[i0 + il];
#pragma unroll
  for (int p = 0; p < 32; ++p) {
    int cp = p * 4 + (tid >> 6);
    float v = fmaf(ac, lsT[cp * 65 + il], bc);
    if (do_relu) v = fmaxf(v, 0.f);
    unsigned short hi, lo;
    bf16split(v, hi, lo);
    size_t d = (((size_t)nB * 512) + l0 + cp) * 1024 + i0 + il;
    dsth[d] = hi;
    dstl[d] = lo;
  }
}

// ---------------------------------------------------------------------------
// conv1 as MFMA GEMM (3-term bf16 split), h1[n][o][l'] += bias. 256x256 tile.
// 1-D grid, XCD-aware decode: lin%8 = x + 2*(n&3) so the 4 o-tiles sharing an
// x-slice co-reside on one XCD.
__global__ __launch_bounds__(512, 2) void conv1_mfma_kernel(
    const unsigned short* __restrict__ wth, const unsigned short* __restrict__ wtl,
    const unsigned short* __restrict__ xh, const unsigned short* __restrict__ xl,
    const float* __restrict__ bias, float* __restrict__ h1) {
  extern __shared__ unsigned short sm[];
  const int tid = threadIdx.x;
  const int wid = tid >> 6, lane = tid & 63;
  const int lin = blockIdx.x;
  const int lb = (lin & 1) * 256;
  const int nB = ((lin >> 1) & 3) | ((lin >> 5) << 2);
  const int ob = ((lin >> 3) & 3) * 256;

  f32x16 acc[4][2];
#pragma unroll
  for (int a = 0; a < 4; ++a)
#pragma unroll
    for (int b = 0; b < 2; ++b)
#pragma unroll
      for (int e = 0; e < 16; ++e) acc[a][b][e] = 0.f;

  auto sf = [&](int c, int plane) -> const unsigned short* {
    int t = c >> 5, kc = c & 31;
    if (plane == 0) return wth + ((((size_t)t << 10) + ob) << 10) + kc * 32;
    if (plane == 1) return wtl + ((((size_t)t << 10) + ob) << 10) + kc * 32;
    const unsigned short* xp = (plane == 2) ? xh : xl;
    return xp + ((((size_t)((t & 1) * 32 + nB) * 512) + lb + (t >> 1)) << 10) + kc * 32;
  };
  mfma256_core32(sf, sm, 128, acc);

  const int wm = wid >> 2, wn = wid & 3;
#pragma unroll
  for (int mt = 0; mt < 4; ++mt) {
#pragma unroll
    for (int nt = 0; nt < 2; ++nt) {
      const int l = lb + (wn << 6) + nt * 32 + (lane & 31);
      if (l < LP) {
#pragma unroll
        for (int rq = 0; rq < 4; ++rq) {
          const int o0 = ob + (wm << 7) + mt * 32 + rq * 8 + ((lane >> 5) << 2);
#pragma unroll
          for (int rg = 0; rg < 4; ++rg)
            h1[((size_t)(nB << 10) + o0 + rg) * LPAD + l] =
                acc[mt][nt][rq * 4 + rg] + bias[o0 + rg];
        }
      }
    }
  }
}

// ---------------------------------------------------------------------------
// conv2 as MFMA GEMM: t2 = h1 + W2 @ r + b2c   (r = pre-split relu(a1*h1+b1))
__global__ __launch_bounds__(512, 2) void conv2_mfma_kernel(
    const unsigned short* __restrict__ w2h, const unsigned short* __restrict__ w2l,
    const unsigned short* __restrict__ rh, const unsigned short* __restrict__ rl,
    const float* __restrict__ b2c, const float* __restrict__ h1,
    float* __restrict__ t2) {
  extern __shared__ unsigned short sm[];
  const int tid = threadIdx.x;
  const int wid = tid >> 6, lane = tid & 63;
  const int lin = blockIdx.x;
  const int lb = (lin & 1) * 256;
  const int nB = ((lin >> 1) & 3) | ((lin >> 5) << 2);
  const int ob = ((lin >> 3) & 3) * 256;

  f32x16 acc[4][2];
#pragma unroll
  for (int a = 0; a < 4; ++a)
#pragma unroll
    for (int b = 0; b < 2; ++b)
#pragma unroll
      for (int e = 0; e < 16; ++e) acc[a][b][e] = 0.f;

  auto sf = [&](int c, int plane) -> const unsigned short* {
    if (plane == 0) return w2h + ((size_t)ob << 10) + (size_t)c * 32;
    if (plane == 1) return w2l + ((size_t)ob << 10) + (size_t)c * 32;
    const unsigned short* rp = (plane == 2) ? rh : rl;
    return rp + (((size_t)nB * 512 + lb) << 10) + (size_t)c * 32;
  };
  mfma256_core32(sf, sm, 32, acc);

  const int wm = wid >> 2, wn = wid & 3;
#pragma unroll
  for (int mt = 0; mt < 4; ++mt) {
#pragma unroll
    for (int nt = 0; nt < 2; ++nt) {
      const int l = lb + (wn << 6) + nt * 32 + (lane & 31);
      if (l < LP) {
#pragma unroll
        for (int rq = 0; rq < 4; ++rq) {
          const int o0 = ob + (wm << 7) + mt * 32 + rq * 8 + ((lane >> 5) << 2);
#pragma unroll
          for (int rg = 0; rg < 4; ++rg) {
            size_t off = ((size_t)(nB << 10) + o0 + rg) * LPAD + l;
            t2[off] = h1[off] + acc[mt][nt][rq * 4 + rg] + b2c[o0 + rg];
          }
        }
      }
    }
  }
}

// ---------------------------------------------------------------------------
// dist as MFMA GEMM: S = cb @ z; argmin_k (e2[k] - 2S) via packed u64 atomicMin
__global__ __launch_bounds__(512, 2) void dist_mfma_kernel(
    const unsigned short* __restrict__ cbh, const unsigned short* __restrict__ cbl,
    const unsigned short* __restrict__ zh, const unsigned short* __restrict__ zl,
    const float* __restrict__ e2, unsigned long long* __restrict__ slots) {
  extern __shared__ unsigned short sm[];
  unsigned long long* best = (unsigned long long*)(sm + 65536);
  const int tid = threadIdx.x;
  const int wid = tid >> 6, lane = tid & 63;
  const int lb = blockIdx.x * 256, kb = blockIdx.y * 256, nB = blockIdx.z;

  if (tid < 256) best[tid] = ~0ULL;

  f32x16 acc[4][2];
#pragma unroll
  for (int a = 0; a < 4; ++a)
#pragma unroll
    for (int b = 0; b < 2; ++b)
#pragma unroll
      for (int e = 0; e < 16; ++e) acc[a][b][e] = 0.f;

  auto sf = [&](int c, int plane) -> const unsigned short* {
    if (plane == 0) return cbh + ((size_t)kb << 10) + (size_t)c * 32;
    if (plane == 1) return cbl + ((size_t)kb << 10) + (size_t)c * 32;
    const unsigned short* zp = (plane == 2) ? zh : zl;
    return zp + (((size_t)nB * 512 + lb) << 10) + (size_t)c * 32;
  };
  mfma256_core32(sf, sm, 32, acc);

  const int wm = wid >> 2, wn = wid & 3;
#pragma unroll
  for (int nt = 0; nt < 2; ++nt) {
    const int col = (wn << 6) + nt * 32 + (lane & 31);
    float dmin = 3.4e38f;
    int kmin = 0;
#pragma unroll
    for (int mt = 0; mt < 4; ++mt) {
#pragma unroll
      for (int rq = 0; rq < 4; ++rq) {
        const int kbase = kb + (wm << 7) + mt * 32 + rq * 8 + ((lane >> 5) << 2);
#pragma unroll
        for (int rg = 0; rg < 4; ++rg) {
          float dist = fmaf(-2.f, acc[mt][nt][rq * 4 + rg], e2[kbase + rg]);
          if (dist < dmin) { dmin = dist; kmin = kbase + rg; }
        }
      }
    }
    unsigned long long pk =
        ((unsigned long long)__float_as_uint(dmin) << 32) | (unsigned)kmin;
    atomicMin(&best[col], pk);
  }
  __syncthreads();
  if (tid < 256) {
    int l = lb + tid;
    if (l < LP) atomicMin(&slots[(size_t)nB * LP + l], best[tid]);
  }
}

// ---------------------------------------------------------------------------
__global__ __launch_bounds__(256) void bn_stats_kernel(
    const float* __restrict__ src, const float* __restrict__ gamma,
    const float* __restrict__ beta, float* __restrict__ a_out,
    float* __restrict__ b_out) {
  __shared__ float sb[4];
  const int c = blockIdx.x;
  const float* p = src + (size_t)c * LPAD;
  float s1 = 0.f, s2 = 0.f;
  for (int idx = threadIdx.x; idx < NBATCH * LP; idx += 256) {
    int nn = idx / LP;
    int l = idx - nn * LP;
    float v = p[(size_t)nn * DD * LPAD + l];
    s1 += v;
    s2 = fmaf(v, v, s2);
  }
  s1 = blockReduce256(s1, sb);
  s2 = blockReduce256(s2, sb);
  if (threadIdx.x == 0) {
    const float inv = 1.f / (float)(NBATCH * LP);
    float m = s1 * inv;
    float var = fmaf(-m, m, s2 * inv);
    float a = gamma[c] * rsqrtf(var + BN_EPS);
    a_out[c] = a;
    b_out[c] = fmaf(-m, a, beta[c]);
  }
}

// ---------------------------------------------------------------------------
__global__ __launch_bounds__(256) void e2_kernel(const float* __restrict__ cb,
                                                 float* __restrict__ e2) {
  __shared__ float sb[4];
  const int k = blockIdx.x;
  float s = 0.f;
  for (int d = threadIdx.x; d < DD; d += 256) {
    float v = cb[(size_t)k * DD + d];
    s = fmaf(v, v, s);
  }
  s = blockReduce256(s, sb);
  if (threadIdx.x == 0) e2[k] = s;
}

// ---------------------------------------------------------------------------
__global__ __launch_bounds__(256) void gather_kernel(
    const float* __restrict__ t2, const float* __restrict__ cb,
    const float* __restrict__ a2, const float* __restrict__ b2,
    const unsigned long long* __restrict__ slots, float* __restrict__ out,
    float* __restrict__ loss_acc) {
  __shared__ int ks[64];
  __shared__ float sb[4];
  const int l0 = blockIdx.x * 64;
  const int n = blockIdx.y;
  const int tid = threadIdx.x, tx = tid & 63, ty = tid >> 6;
  if (tid < 64) {
    int l = l0 + tid;
    int k = 0;
    if (l < LP) {
      k = (int)(unsigned)(slots[(size_t)n * LP + l] & 0xffffffffULL);
      out[OUT_IDS + (size_t)n * LP + l] = (float)k;
    }
    ks[tid] = k;
  }
  __syncthreads();
  const int l = l0 + tx;
  const bool valid = (l < LP);
  const int k = ks[tx];
  const float* cbk = cb + (size_t)k * DD;
  const float* tn = t2 + (size_t)n * DD * LPAD;
  float* qo = out + (size_t)n * DD * LP;
  float lsum = 0.f;
  for (int d0 = 0; d0 < DD; d0 += 4) {
    const int d = d0 + ty;
    float q = cbk[d];
    if (valid) {
      float z = fmaf(a2[d], tn[(size_t)d * LPAD + l], b2[d]);
      qo[(size_t)d * LP + l] = q;
      float e = z - q;
      lsum = fmaf(e, e, lsum);
    }
  }
  lsum = blockReduce256(lsum, sb);
  if (tid == 0) atomicAdd(loss_acc, lsum);
}

__global__ void finalize_kernel(const float* __restrict__ loss_acc,
                                float* __restrict__ out) {
  if (threadIdx.x == 0) {
    float m = loss_acc[0] * (1.f / 16744448.f);
    out[OUT_LOSS] = m;
    out[OUT_LOSS + 1] = m;
  }
}

// ---------------------------------------------------------------------------
extern "C" void kernel_launch(void* const* d_in, const int* in_sizes, int n_in,
                              void* d_out, int out_size, void* d_ws,
                              size_t ws_size, hipStream_t stream) {
  const float* x = (const float*)d_in[0];
  const float* w1 = (const float*)d_in[1];
  const float* b1c = (const float*)d_in[2];
  const float* g1 = (const float*)d_in[3];
  const float* be1 = (const float*)d_in[4];
  const float* w2 = (const float*)d_in[5];
  const float* b2c = (const float*)d_in[6];
  const float* g2 = (const float*)d_in[7];
  const float* be2 = (const float*)d_in[8];
  const float* cb = (const float*)d_in[9];
  float* out = (float*)d_out;
  float* ws = (float*)d_ws;

  float* h1 = ws + WS_H1;
  float* t2 = ws + WS_T2;
  unsigned short* xh = (unsigned short*)(ws + WS_XH);
  unsigned short* xl = (unsigned short*)(ws + WS_XL);
  unsigned short* wth = (unsigned short*)(ws + WS_WTH);
  unsigned short* wtl = (unsigned short*)(ws + WS_WTL);
  unsigned short* rh = (unsigned short*)(ws + WS_RH);
  unsigned short* rl = (unsigned short*)(ws + WS_RL);
  unsigned short* zh = (unsigned short*)(ws + WS_ZH);
  unsigned short* zl = (unsigned short*)(ws + WS_ZL);
  unsigned short* w2h = (unsigned short*)(ws + WS_W2H);
  unsigned short* w2l = (unsigned short*)(ws + WS_W2L);
  unsigned short* cbh = (unsigned short*)(ws + WS_CBH);
  unsigned short* cbl = (unsigned short*)(ws + WS_CBL);
  float* a1 = ws + WS_A1;
  float* bb1 = ws + WS_B1;
  float* a2 = ws + WS_A2;
  float* bb2 = ws + WS_B2;
  float* e2 = ws + WS_E2;
  unsigned long long* slots = (unsigned long long*)(ws + WS_SLOTS);
  float* loss = ws + WS_LOSS;

  static int attr_done = 0;
  if (!attr_done) {
    (void)hipFuncSetAttribute(reinterpret_cast<const void*>(conv1_mfma_kernel),
                              hipFuncAttributeMaxDynamicSharedMemorySize, 135168);
    (void)hipFuncSetAttribute(reinterpret_cast<const void*>(conv2_mfma_kernel),
                              hipFuncAttributeMaxDynamicSharedMemorySize, 135168);
    (void)hipFuncSetAttribute(reinterpret_cast<const void*>(dist_mfma_kernel),
                              hipFuncAttributeMaxDynamicSharedMemorySize, 135168);
    attr_done = 1;
  }

  (void)hipMemsetAsync(slots, 0xFF,
                       (size_t)NBATCH * LP * sizeof(unsigned long long), stream);
  (void)hipMemsetAsync(loss, 0, sizeof(float), stream);

  // phase 0: conv1 operand prep + conv1
  split_w1_kernel<<<4096, 256, 0, stream>>>(w1, wth, wtl);
  split_x_kernel<<<dim3(8, 16, NBATCH), 256, 0, stream>>>(x, xh, xl);
  conv1_mfma_kernel<<<256, 512, 131072, stream>>>(wth, wtl, xh, xl, b1c, h1);
  // phase 1: BN1 stats, then conv2 operand prep (overlays dead conv1 planes)
  bn_stats_kernel<<<DD, 256, 0, stream>>>(h1, g1, be1, a1, bb1);
  split_rows_kernel<<<1024, 256, 0, stream>>>(w2, w2h, w2l);
  split_rows_kernel<<<2048, 256, 0, stream>>>(cb, cbh, cbl);
  e2_kernel<<<KCB, 256, 0, stream>>>(cb, e2);
  trans_affine_split_kernel<<<dim3(4, 16, NBATCH), 256, 0, stream>>>(
      h1, a1, bb1, rh, rl, 1);
  conv2_mfma_kernel<<<256, 512, 131072, stream>>>(w2h, w2l, rh, rl, b2c, h1, t2);
  // phase 2: BN2 stats, z prep (overlays dead r planes), dist, gather
  bn_stats_kernel<<<DD, 256, 0, stream>>>(t2, g2, be2, a2, bb2);
  trans_affine_split_kernel<<<dim3(4, 16, NBATCH), 256, 0, stream>>>(
      t2, a2, bb2, zh, zl, 0);
  dist_mfma_kernel<<<dim3(2, 8, NBATCH), 512, 133120, stream>>>(cbh, cbl, zh,
                                                                zl, e2, slots);
  gather_kernel<<<dim3(8, NBATCH), 256, 0, stream>>>(t2, cb, a2, bb2, slots, out, loss);
  finalize_kernel<<<1, 64, 0, stream>>>(loss, out);
}

// Round 4
// 977.691 us; speedup vs baseline: 1.5201x; 1.5201x over previous
//
#include <hip/hip_runtime.h>
#include <hip/hip_bf16.h>
#include <cstdint>

// Problem dims
#define DD 1024
#define LIN 1024
#define LP 511
#define LPAD 512
#define NBATCH 32
#define KCB 2048
#define BN_EPS 1e-5f

// Output layout (floats): q_st [32,1024,511], ids [32,511], commitment, codebook_loss
#define OUT_IDS 16744448u
#define OUT_LOSS 16760800u

// Workspace layout (float offsets). Region X = [WS_UNI, WS_AUX) is
// phase-multiplexed: phase0 conv1 operands; phase2 t2 + r/z planes + small planes.
#define WS_H1 0
#define WS_UNI 16777216
// phase0 (conv1):
#define WS_XH  (WS_UNI)                    // [2][32][512][1024] ushort (+512 f pad)
#define WS_XL  (WS_UNI + 16777728)
#define WS_WTH (WS_UNI + 33555456)         // [4][1024][1024] ushort
#define WS_WTL (WS_UNI + 35652608)
// phase2 (after conv1 done):
#define WS_T2  (WS_UNI)                    // fp32 [32][1024][512]
#define WS_RH  (WS_UNI + 16777216)         // [32][512][1024] ushort
#define WS_RL  (WS_UNI + 25165824)
#define WS_ZH  WS_RH                       // reuse after conv2 done
#define WS_ZL  WS_RL
#define WS_W2H (WS_UNI + 33554432)         // [1024][1024] ushort
#define WS_W2L (WS_UNI + 34078720)
#define WS_CBH (WS_UNI + 34603008)         // [2048][1024] ushort
#define WS_CBL (WS_UNI + 35651584)
#define WS_AUX (WS_UNI + 37749760)
#define WS_A1 (WS_AUX + 0)
#define WS_B1 (WS_AUX + 1024)
#define WS_A2 (WS_AUX + 2048)
#define WS_B2 (WS_AUX + 3072)
#define WS_E2 (WS_AUX + 4096)
#define WS_SLOTS (WS_AUX + 6144)
#define WS_LOSS (WS_AUX + 6144 + 32704)

typedef __attribute__((ext_vector_type(8))) short bf16x8;
typedef __attribute__((ext_vector_type(4))) float f32x4;
typedef __attribute__((ext_vector_type(4))) unsigned short ushort4v;
typedef __attribute__((ext_vector_type(8))) unsigned short ushort8v;

__device__ __forceinline__ void async_cp16(const void* gsrc, void* ldst) {
  __builtin_amdgcn_global_load_lds(
      (const __attribute__((address_space(1))) unsigned int*)gsrc,
      (__attribute__((address_space(3))) unsigned int*)ldst, 16, 0, 0);
}

__device__ __forceinline__ void bf16split(float v, unsigned short& hi, unsigned short& lo) {
  __hip_bfloat16 h = __float2bfloat16(v);
  float hf = __bfloat162float(h);
  __hip_bfloat16 l = __float2bfloat16(v - hf);
  hi = *(unsigned short*)&h;
  lo = *(unsigned short*)&l;
}

__device__ inline float blockReduce256(float v, float* sb) {
#pragma unroll
  for (int off = 32; off > 0; off >>= 1) v += __shfl_down(v, off);
  __syncthreads();
  if ((threadIdx.x & 63) == 0) sb[threadIdx.x >> 6] = v;
  __syncthreads();
  return sb[0] + sb[1] + sb[2] + sb[3];
}

#define VMCNT(n) asm volatile("s_waitcnt vmcnt(" #n ")" ::: "memory")

// ---------------------------------------------------------------------------
// 256x256 tile MFMA core, 512 threads = 8 waves (2M x 4N), wave tile 128x64.
// 4 planes per K=32 chunk in LDS: Ah(0), Al(8192), Bh(16384), Bl(24576)
// halfword offsets; 256 rows x 32 halfwords per plane; double-buffered
// (buffer stride 32768 halfwords = 64 KB; total 128 KB).
//
// Swizzle: 16B slot s within each 64B row stored at s ^ ((row>>1)&3).
// Applied by pre-swizzling the GLOBAL source of global_load_lds (LDS dest
// stays linear) and by the same XOR on the read side -> conflict-free
// (measured 0 SQ_LDS_BANK_CONFLICT with the 16x16 read pattern).
//
// Stage slots per wave per chunk (8 x 1KB units, issue order = consumption
// order): 0:Bh rows 16w, 1:Bh 128+16w, 2:Bl 16w, 3:Bl 128+16w, 4..7: A phase
// p=slot-4 unit (plane by w&1, half by (w>>1)&1, j by w>>2). Next-chunk
// phase-0 needs slots 0..4; phase p needs slot 4+p.  Steady-state waits:
// phase p entry -> vmcnt(3+p) (issued 8+2p, oldest 5+p done). Last chunk
// (no prefetch): vmcnt(3-p).
template <typename SF>
__device__ __forceinline__ void stage_slot(const SF& sf, int c, int slot,
                                           unsigned short* smbase, int wid,
                                           int lane) {
  int plane, r0;
  if (slot < 4) {
    plane = 2 + (slot >> 1);
    r0 = ((slot & 1) << 7) + (wid << 4);
  } else {
    plane = wid & 1;
    r0 = (((wid >> 1) & 1) << 7) + ((slot - 4) << 5) + ((wid >> 2) << 4);
  }
  const unsigned short* g = sf(c, plane) + (size_t)(r0 + (lane >> 2)) * 1024 +
                            (((lane & 3) ^ ((lane >> 3) & 3)) << 3);
  unsigned short* d = smbase + plane * 8192 + r0 * 32;  // HW adds lane*16B
  async_cp16(g, d);
}

template <typename SF>
__device__ __forceinline__ void mfma256_core(const SF& sf, unsigned short* sm,
                                             int nkc, f32x4 (&acc)[8][4]) {
  const int tid = threadIdx.x;
  const int wid = tid >> 6, lane = tid & 63;
  const int wm = wid >> 2, wn = wid & 3;
  // swizzled 16B-slot halfword offset; sigma = ((row>>1)&3) = ((lane>>1)&3)
  // since all fragment row-bases are multiples of 16.
  const int slot16 = (((lane >> 4) ^ ((lane >> 1) & 3)) << 3);
  const int arow = (wm << 7) + (lane & 15);
  const int brow = (wn << 6) + (lane & 15);

  // prologue: chunk 0's 8 slots in order
#pragma unroll
  for (int s = 0; s < 8; ++s) stage_slot(sf, 0, s, sm, wid, lane);

  bf16x8 fbh[4], fbl[4];
  for (int c = 0; c < nkc; ++c) {
    unsigned short* buf = sm + ((c & 1) << 15);
    unsigned short* nbuf = sm + (((c + 1) & 1) << 15);
    const unsigned short* As = buf;
    const unsigned short* Als = buf + 8192;
    const unsigned short* Bs = buf + 16384;
    const unsigned short* Bls = buf + 24576;
    const bool pre = (c + 1 < nkc);
#pragma unroll
    for (int p = 0; p < 4; ++p) {
      if (pre) {
        if (p == 0) { VMCNT(3); } else if (p == 1) { VMCNT(4); }
        else if (p == 2) { VMCNT(5); } else { VMCNT(6); }
      } else {
        if (p == 0) { VMCNT(3); } else if (p == 1) { VMCNT(2); }
        else if (p == 2) { VMCNT(1); } else { VMCNT(0); }
      }
      __builtin_amdgcn_s_barrier();
      asm volatile("" ::: "memory");
      __builtin_amdgcn_sched_barrier(0);
      if (p == 0) {
#pragma unroll
        for (int nt = 0; nt < 4; ++nt) {
          int r = brow + nt * 16;
          fbh[nt] = *(const bf16x8*)(Bs + r * 32 + slot16);
          fbl[nt] = *(const bf16x8*)(Bls + r * 32 + slot16);
        }
      }
      bf16x8 fah0, fal0, fah1, fal1;
      {
        int r0 = arow + ((2 * p) << 4);
        int r1 = r0 + 16;
        fah0 = *(const bf16x8*)(As + r0 * 32 + slot16);
        fal0 = *(const bf16x8*)(Als + r0 * 32 + slot16);
        fah1 = *(const bf16x8*)(As + r1 * 32 + slot16);
        fal1 = *(const bf16x8*)(Als + r1 * 32 + slot16);
      }
      if (pre) {
        stage_slot(sf, c + 1, 2 * p + 0, nbuf, wid, lane);
        stage_slot(sf, c + 1, 2 * p + 1, nbuf, wid, lane);
      }
      __builtin_amdgcn_s_setprio(1);
#pragma unroll
      for (int nt = 0; nt < 4; ++nt) {
        acc[2 * p][nt] = __builtin_amdgcn_mfma_f32_16x16x32_bf16(fah0, fbh[nt], acc[2 * p][nt], 0, 0, 0);
        acc[2 * p][nt] = __builtin_amdgcn_mfma_f32_16x16x32_bf16(fah0, fbl[nt], acc[2 * p][nt], 0, 0, 0);
        acc[2 * p][nt] = __builtin_amdgcn_mfma_f32_16x16x32_bf16(fal0, fbh[nt], acc[2 * p][nt], 0, 0, 0);
      }
#pragma unroll
      for (int nt = 0; nt < 4; ++nt) {
        acc[2 * p + 1][nt] = __builtin_amdgcn_mfma_f32_16x16x32_bf16(fah1, fbh[nt], acc[2 * p + 1][nt], 0, 0, 0);
        acc[2 * p + 1][nt] = __builtin_amdgcn_mfma_f32_16x16x32_bf16(fah1, fbl[nt], acc[2 * p + 1][nt], 0, 0, 0);
        acc[2 * p + 1][nt] = __builtin_amdgcn_mfma_f32_16x16x32_bf16(fal1, fbh[nt], acc[2 * p + 1][nt], 0, 0, 0);
      }
      __builtin_amdgcn_s_setprio(0);
    }
  }
}

// ---------------------------------------------------------------------------
// split w1 [o][i][t] fp32 -> wth/wtl [t][o][i] bf16 hi/lo
__global__ __launch_bounds__(256) void split_w1_kernel(
    const float* __restrict__ w, unsigned short* __restrict__ wth,
    unsigned short* __restrict__ wtl) {
  int idx = blockIdx.x * 256 + threadIdx.x;
  int o = idx >> 10, i = idx & 1023;
  float4 v = *(const float4*)&w[(size_t)idx * 4];
  float vv[4] = {v.x, v.y, v.z, v.w};
#pragma unroll
  for (int t = 0; t < 4; ++t) {
    unsigned short hi, lo;
    bf16split(vv[t], hi, lo);
    size_t off = (((size_t)(t << 10) + o) << 10) + i;
    wth[off] = hi;
    wtl[off] = lo;
  }
}

// ---------------------------------------------------------------------------
// generic row-major split: src [rows][1024] fp32 -> dsth/dstl bf16 hi/lo
__global__ __launch_bounds__(256) void split_rows_kernel(
    const float* __restrict__ src, unsigned short* __restrict__ dsth,
    unsigned short* __restrict__ dstl) {
  size_t base = ((size_t)blockIdx.x * 256 + threadIdx.x) * 4;
  float4 v = *(const float4*)&src[base];
  float vv[4] = {v.x, v.y, v.z, v.w};
  ushort4v h, l;
#pragma unroll
  for (int j = 0; j < 4; ++j) {
    unsigned short hi, lo;
    bf16split(vv[j], hi, lo);
    h[j] = hi;
    l[j] = lo;
  }
  *(ushort4v*)&dsth[base] = h;
  *(ushort4v*)&dstl[base] = l;
}

// ---------------------------------------------------------------------------
// split/transpose x [n][i][l] fp32 -> xh/xl [P][n][l>>1][i] bf16 (P = l&1)
// Consumer side vectorized: each lane emits 8 consecutive channels -> 16B
// ushort8 stores per plane.
__global__ __launch_bounds__(256) void split_x_kernel(
    const float* __restrict__ x, unsigned short* __restrict__ xh,
    unsigned short* __restrict__ xl) {
  __shared__ float lsT[128 * 65];
  const int l0 = blockIdx.x * 128;
  const int i0 = blockIdx.y * 64;
  const int nB = blockIdx.z;
  const int tid = threadIdx.x;
#pragma unroll
  for (int p = 0; p < 8; ++p) {
    int flat = p * 256 + tid;
    int row = flat >> 5, col4 = (flat & 31) * 4;
    float4 v = *(const float4*)&x[((size_t)nB * DD + i0 + row) * LIN + l0 + col4];
    lsT[(col4 + 0) * 65 + row] = v.x;
    lsT[(col4 + 1) * 65 + row] = v.y;
    lsT[(col4 + 2) * 65 + row] = v.z;
    lsT[(col4 + 3) * 65 + row] = v.w;
  }
  __syncthreads();
  const int lo2 = (l0 >> 1);
  const int ilg = (tid & 7) * 8;   // 8-channel group
  const int q = tid >> 3;          // 0..31
#pragma unroll
  for (int p = 0; p < 4; ++p) {
    const int idx = p * 32 + q;    // l-column 0..127
    const int par = idx & 1, cp = idx >> 1;
    ushort8v hv, lv;
#pragma unroll
    for (int j = 0; j < 8; ++j) {
      unsigned short hi, lo;
      bf16split(lsT[idx * 65 + ilg + j], hi, lo);
      hv[j] = hi;
      lv[j] = lo;
    }
    size_t d = (((size_t)(par * 32 + nB) * 512) + lo2 + cp) * 1024 + i0 + ilg;
    *(ushort8v*)&xh[d] = hv;
    *(ushort8v*)&xl[d] = lv;
  }
}

// ---------------------------------------------------------------------------
// transpose + per-channel affine (+optional relu) + bf16 split:
// src [n][c][LPAD] fp32 -> dsth/dstl [n][LPAD][1024] bf16 hi/lo of (a*v+b)
// Consumer side vectorized: 16B ushort8 stores per plane.
__global__ __launch_bounds__(256) void trans_affine_split_kernel(
    const float* __restrict__ src, const float* __restrict__ a,
    const float* __restrict__ b, unsigned short* __restrict__ dsth,
    unsigned short* __restrict__ dstl, int do_relu) {
  __shared__ float lsT[128 * 65];
  const int l0 = blockIdx.x * 128;
  const int i0 = blockIdx.y * 64;
  const int nB = blockIdx.z;
  const int tid = threadIdx.x;
#pragma unroll
  for (int p = 0; p < 8; ++p) {
    int flat = p * 256 + tid;
    int row = flat >> 5, col4 = (flat & 31) * 4;
    float4 v = *(const float4*)&src[((size_t)nB * DD + i0 + row) * LPAD + l0 + col4];
    lsT[(col4 + 0) * 65 + row] = v.x;
    lsT[(col4 + 1) * 65 + row] = v.y;
    lsT[(col4 + 2) * 65 + row] = v.z;
    lsT[(col4 + 3) * 65 + row] = v.w;
  }
  __syncthreads();
  const int ilg = (tid & 7) * 8;
  const int q = tid >> 3;  // 0..31
  float4 a0 = *(const float4*)&a[i0 + ilg];
  float4 a1 = *(const float4*)&a[i0 + ilg + 4];
  float4 b0 = *(const float4*)&b[i0 + ilg];
  float4 b1 = *(const float4*)&b[i0 + ilg + 4];
  float ac[8] = {a0.x, a0.y, a0.z, a0.w, a1.x, a1.y, a1.z, a1.w};
  float bc[8] = {b0.x, b0.y, b0.z, b0.w, b1.x, b1.y, b1.z, b1.w};
#pragma unroll
  for (int p = 0; p < 4; ++p) {
    const int cp = p * 32 + q;
    ushort8v hv, lv;
#pragma unroll
    for (int j = 0; j < 8; ++j) {
      float v = fmaf(ac[j], lsT[cp * 65 + ilg + j], bc[j]);
      if (do_relu) v = fmaxf(v, 0.f);
      unsigned short hi, lo;
      bf16split(v, hi, lo);
      hv[j] = hi;
      lv[j] = lo;
    }
    size_t d = (((size_t)nB * 512) + l0 + cp) * 1024 + i0 + ilg;
    *(ushort8v*)&dsth[d] = hv;
    *(ushort8v*)&dstl[d] = lv;
  }
}

// ---------------------------------------------------------------------------
// conv1 as MFMA GEMM (3-term bf16 split), h1[n][o][l'] += bias. 256x256 tile.
// 1-D grid, XCD-aware decode: lin%8 = x + 2*(n&3) so the 4 o-tiles sharing an
// x-slice co-reside on one XCD (x-slice L2-resident, fetched once).
__global__ __launch_bounds__(512, 2) void conv1_mfma_kernel(
    const unsigned short* __restrict__ wth, const unsigned short* __restrict__ wtl,
    const unsigned short* __restrict__ xh, const unsigned short* __restrict__ xl,
    const float* __restrict__ bias, float* __restrict__ h1) {
  extern __shared__ unsigned short sm[];
  const int tid = threadIdx.x;
  const int wid = tid >> 6, lane = tid & 63;
  const int lin = blockIdx.x;
  const int lb = (lin & 1) * 256;
  const int nB = ((lin >> 1) & 3) | ((lin >> 5) << 2);
  const int ob = ((lin >> 3) & 3) * 256;

  f32x4 acc[8][4];
#pragma unroll
  for (int a = 0; a < 8; ++a)
#pragma unroll
    for (int b = 0; b < 4; ++b) acc[a][b] = (f32x4){0.f, 0.f, 0.f, 0.f};

  auto sf = [&](int c, int plane) -> const unsigned short* {
    int t = c >> 5, kc = c & 31;
    if (plane == 0) return wth + ((((size_t)t << 10) + ob) << 10) + kc * 32;
    if (plane == 1) return wtl + ((((size_t)t << 10) + ob) << 10) + kc * 32;
    const unsigned short* xp = (plane == 2) ? xh : xl;
    return xp + ((((size_t)((t & 1) * 32 + nB) * 512) + lb + (t >> 1)) << 10) + kc * 32;
  };
  mfma256_core(sf, sm, 128, acc);

  const int wm = wid >> 2, wn = wid & 3;
#pragma unroll
  for (int mt = 0; mt < 8; ++mt) {
    const int o_base = ob + (wm << 7) + mt * 16 + ((lane >> 4) << 2);
#pragma unroll
    for (int nt = 0; nt < 4; ++nt) {
      const int l = lb + (wn << 6) + nt * 16 + (lane & 15);
      if (l < LP) {
#pragma unroll
        for (int rg = 0; rg < 4; ++rg)
          h1[((size_t)(nB << 10) + o_base + rg) * LPAD + l] =
              acc[mt][nt][rg] + bias[o_base + rg];
      }
    }
  }
}

// ---------------------------------------------------------------------------
// conv2 as MFMA GEMM: t2 = h1 + W2 @ r + b2c   (r = pre-split relu(a1*h1+b1))
__global__ __launch_bounds__(512, 2) void conv2_mfma_kernel(
    const unsigned short* __restrict__ w2h, const unsigned short* __restrict__ w2l,
    const unsigned short* __restrict__ rh, const unsigned short* __restrict__ rl,
    const float* __restrict__ b2c, const float* __restrict__ h1,
    float* __restrict__ t2) {
  extern __shared__ unsigned short sm[];
  const int tid = threadIdx.x;
  const int wid = tid >> 6, lane = tid & 63;
  const int lin = blockIdx.x;
  const int lb = (lin & 1) * 256;
  const int nB = ((lin >> 1) & 3) | ((lin >> 5) << 2);
  const int ob = ((lin >> 3) & 3) * 256;

  f32x4 acc[8][4];
#pragma unroll
  for (int a = 0; a < 8; ++a)
#pragma unroll
    for (int b = 0; b < 4; ++b) acc[a][b] = (f32x4){0.f, 0.f, 0.f, 0.f};

  auto sf = [&](int c, int plane) -> const unsigned short* {
    if (plane == 0) return w2h + ((size_t)ob << 10) + (size_t)c * 32;
    if (plane == 1) return w2l + ((size_t)ob << 10) + (size_t)c * 32;
    const unsigned short* rp = (plane == 2) ? rh : rl;
    return rp + (((size_t)nB * 512 + lb) << 10) + (size_t)c * 32;
  };
  mfma256_core(sf, sm, 32, acc);

  const int wm = wid >> 2, wn = wid & 3;
#pragma unroll
  for (int mt = 0; mt < 8; ++mt) {
    const int o_base = ob + (wm << 7) + mt * 16 + ((lane >> 4) << 2);
#pragma unroll
    for (int nt = 0; nt < 4; ++nt) {
      const int l = lb + (wn << 6) + nt * 16 + (lane & 15);
      if (l < LP) {
#pragma unroll
        for (int rg = 0; rg < 4; ++rg) {
          size_t off = ((size_t)(nB << 10) + o_base + rg) * LPAD + l;
          t2[off] = h1[off] + acc[mt][nt][rg] + b2c[o_base + rg];
        }
      }
    }
  }
}

// ---------------------------------------------------------------------------
// dist as MFMA GEMM: S = cb @ z; argmin_k (e2[k] - 2S) via packed u64 atomicMin
// 1-D grid, XCD decode: lin%8 = l-tile + 2*(n&3).
__global__ __launch_bounds__(512, 2) void dist_mfma_kernel(
    const unsigned short* __restrict__ cbh, const unsigned short* __restrict__ cbl,
    const unsigned short* __restrict__ zh, const unsigned short* __restrict__ zl,
    const float* __restrict__ e2, unsigned long long* __restrict__ slots) {
  extern __shared__ unsigned short sm[];
  unsigned long long* best = (unsigned long long*)(sm + 65536);
  const int tid = threadIdx.x;
  const int wid = tid >> 6, lane = tid & 63;
  const int lin = blockIdx.x;
  const int lb = (lin & 1) * 256;
  const int nB = ((lin >> 1) & 3) | ((lin >> 6) << 2);
  const int kb = ((lin >> 3) & 7) * 256;

  if (tid < 256) best[tid] = ~0ULL;

  f32x4 acc[8][4];
#pragma unroll
  for (int a = 0; a < 8; ++a)
#pragma unroll
    for (int b = 0; b < 4; ++b) acc[a][b] = (f32x4){0.f, 0.f, 0.f, 0.f};

  auto sf = [&](int c, int plane) -> const unsigned short* {
    if (plane == 0) return cbh + ((size_t)kb << 10) + (size_t)c * 32;
    if (plane == 1) return cbl + ((size_t)kb << 10) + (size_t)c * 32;
    const unsigned short* zp = (plane == 2) ? zh : zl;
    return zp + (((size_t)nB * 512 + lb) << 10) + (size_t)c * 32;
  };
  mfma256_core(sf, sm, 32, acc);

  const int wm = wid >> 2, wn = wid & 3;
#pragma unroll
  for (int nt = 0; nt < 4; ++nt) {
    const int col = (wn << 6) + nt * 16 + (lane & 15);
    float dmin = 3.4e38f;
    int kmin = 0;
#pragma unroll
    for (int mt = 0; mt < 8; ++mt) {
      const int kbase = kb + (wm << 7) + mt * 16 + ((lane >> 4) << 2);
#pragma unroll
      for (int rg = 0; rg < 4; ++rg) {
        float dist = fmaf(-2.f, acc[mt][nt][rg], e2[kbase + rg]);
        if (dist < dmin) { dmin = dist; kmin = kbase + rg; }
      }
    }
    unsigned long long pk =
        ((unsigned long long)__float_as_uint(dmin) << 32) | (unsigned)kmin;
    atomicMin(&best[col], pk);
  }
  __syncthreads();
  if (tid < 256) {
    int l = lb + tid;
    if (l < LP) atomicMin(&slots[(size_t)nB * LP + l], best[tid]);
  }
}

// ---------------------------------------------------------------------------
__global__ __launch_bounds__(256) void bn_stats_kernel(
    const float* __restrict__ src, const float* __restrict__ gamma,
    const float* __restrict__ beta, float* __restrict__ a_out,
    float* __restrict__ b_out) {
  __shared__ float sb[4];
  const int c = blockIdx.x;
  const float* p = src + (size_t)c * LPAD;
  float s1 = 0.f, s2 = 0.f;
  for (int idx = threadIdx.x; idx < NBATCH * LP; idx += 256) {
    int nn = idx / LP;
    int l = idx - nn * LP;
    float v = p[(size_t)nn * DD * LPAD + l];
    s1 += v;
    s2 = fmaf(v, v, s2);
  }
  s1 = blockReduce256(s1, sb);
  s2 = blockReduce256(s2, sb);
  if (threadIdx.x == 0) {
    const float inv = 1.f / (float)(NBATCH * LP);
    float m = s1 * inv;
    float var = fmaf(-m, m, s2 * inv);
    float a = gamma[c] * rsqrtf(var + BN_EPS);
    a_out[c] = a;
    b_out[c] = fmaf(-m, a, beta[c]);
  }
}

// ---------------------------------------------------------------------------
__global__ __launch_bounds__(256) void e2_kernel(const float* __restrict__ cb,
                                                 float* __restrict__ e2) {
  __shared__ float sb[4];
  const int k = blockIdx.x;
  float s = 0.f;
  for (int d = threadIdx.x; d < DD; d += 256) {
    float v = cb[(size_t)k * DD + d];
    s = fmaf(v, v, s);
  }
  s = blockReduce256(s, sb);
  if (threadIdx.x == 0) e2[k] = s;
}

// ---------------------------------------------------------------------------
__global__ __launch_bounds__(256) void gather_kernel(
    const float* __restrict__ t2, const float* __restrict__ cb,
    const float* __restrict__ a2, const float* __restrict__ b2,
    const unsigned long long* __restrict__ slots, float* __restrict__ out,
    float* __restrict__ loss_acc) {
  __shared__ int ks[64];
  __shared__ float sb[4];
  const int l0 = blockIdx.x * 64;
  const int n = blockIdx.y;
  const int tid = threadIdx.x, tx = tid & 63, ty = tid >> 6;
  if (tid < 64) {
    int l = l0 + tid;
    int k = 0;
    if (l < LP) {
      k = (int)(unsigned)(slots[(size_t)n * LP + l] & 0xffffffffULL);
      out[OUT_IDS + (size_t)n * LP + l] = (float)k;
    }
    ks[tid] = k;
  }
  __syncthreads();
  const int l = l0 + tx;
  const bool valid = (l < LP);
  const int k = ks[tx];
  const float* cbk = cb + (size_t)k * DD;
  const float* tn = t2 + (size_t)n * DD * LPAD;
  float* qo = out + (size_t)n * DD * LP;
  float lsum = 0.f;
  for (int d0 = 0; d0 < DD; d0 += 4) {
    const int d = d0 + ty;
    float q = cbk[d];
    if (valid) {
      float z = fmaf(a2[d], tn[(size_t)d * LPAD + l], b2[d]);
      qo[(size_t)d * LP + l] = q;
      float e = z - q;
      lsum = fmaf(e, e, lsum);
    }
  }
  lsum = blockReduce256(lsum, sb);
  if (tid == 0) atomicAdd(loss_acc, lsum);
}

__global__ void finalize_kernel(const float* __restrict__ loss_acc,
                                float* __restrict__ out) {
  if (threadIdx.x == 0) {
    float m = loss_acc[0] * (1.f / 16744448.f);
    out[OUT_LOSS] = m;
    out[OUT_LOSS + 1] = m;
  }
}

// ---------------------------------------------------------------------------
extern "C" void kernel_launch(void* const* d_in, const int* in_sizes, int n_in,
                              void* d_out, int out_size, void* d_ws,
                              size_t ws_size, hipStream_t stream) {
  const float* x = (const float*)d_in[0];
  const float* w1 = (const float*)d_in[1];
  const float* b1c = (const float*)d_in[2];
  const float* g1 = (const float*)d_in[3];
  const float* be1 = (const float*)d_in[4];
  const float* w2 = (const float*)d_in[5];
  const float* b2c = (const float*)d_in[6];
  const float* g2 = (const float*)d_in[7];
  const float* be2 = (const float*)d_in[8];
  const float* cb = (const float*)d_in[9];
  float* out = (float*)d_out;
  float* ws = (float*)d_ws;

  float* h1 = ws + WS_H1;
  float* t2 = ws + WS_T2;
  unsigned short* xh = (unsigned short*)(ws + WS_XH);
  unsigned short* xl = (unsigned short*)(ws + WS_XL);
  unsigned short* wth = (unsigned short*)(ws + WS_WTH);
  unsigned short* wtl = (unsigned short*)(ws + WS_WTL);
  unsigned short* rh = (unsigned short*)(ws + WS_RH);
  unsigned short* rl = (unsigned short*)(ws + WS_RL);
  unsigned short* zh = (unsigned short*)(ws + WS_ZH);
  unsigned short* zl = (unsigned short*)(ws + WS_ZL);
  unsigned short* w2h = (unsigned short*)(ws + WS_W2H);
  unsigned short* w2l = (unsigned short*)(ws + WS_W2L);
  unsigned short* cbh = (unsigned short*)(ws + WS_CBH);
  unsigned short* cbl = (unsigned short*)(ws + WS_CBL);
  float* a1 = ws + WS_A1;
  float* bb1 = ws + WS_B1;
  float* a2 = ws + WS_A2;
  float* bb2 = ws + WS_B2;
  float* e2 = ws + WS_E2;
  unsigned long long* slots = (unsigned long long*)(ws + WS_SLOTS);
  float* loss = ws + WS_LOSS;

  static int attr_done = 0;
  if (!attr_done) {
    (void)hipFuncSetAttribute(reinterpret_cast<const void*>(conv1_mfma_kernel),
                              hipFuncAttributeMaxDynamicSharedMemorySize, 135168);
    (void)hipFuncSetAttribute(reinterpret_cast<const void*>(conv2_mfma_kernel),
                              hipFuncAttributeMaxDynamicSharedMemorySize, 135168);
    (void)hipFuncSetAttribute(reinterpret_cast<const void*>(dist_mfma_kernel),
                              hipFuncAttributeMaxDynamicSharedMemorySize, 135168);
    attr_done = 1;
  }

  (void)hipMemsetAsync(slots, 0xFF,
                       (size_t)NBATCH * LP * sizeof(unsigned long long), stream);
  (void)hipMemsetAsync(loss, 0, sizeof(float), stream);

  // phase 0: conv1 operand prep + conv1
  split_w1_kernel<<<4096, 256, 0, stream>>>(w1, wth, wtl);
  split_x_kernel<<<dim3(8, 16, NBATCH), 256, 0, stream>>>(x, xh, xl);
  conv1_mfma_kernel<<<256, 512, 131072, stream>>>(wth, wtl, xh, xl, b1c, h1);
  // phase 1: BN1 stats, then conv2 operand prep (overlays dead conv1 planes)
  bn_stats_kernel<<<DD, 256, 0, stream>>>(h1, g1, be1, a1, bb1);
  split_rows_kernel<<<1024, 256, 0, stream>>>(w2, w2h, w2l);
  split_rows_kernel<<<2048, 256, 0, stream>>>(cb, cbh, cbl);
  e2_kernel<<<KCB, 256, 0, stream>>>(cb, e2);
  trans_affine_split_kernel<<<dim3(4, 16, NBATCH), 256, 0, stream>>>(
      h1, a1, bb1, rh, rl, 1);
  conv2_mfma_kernel<<<256, 512, 131072, stream>>>(w2h, w2l, rh, rl, b2c, h1, t2);
  // phase 2: BN2 stats, z prep (overlays dead r planes), dist, gather
  bn_stats_kernel<<<DD, 256, 0, stream>>>(t2, g2, be2, a2, bb2);
  trans_affine_split_kernel<<<dim3(4, 16, NBATCH), 256, 0, stream>>>(
      t2, a2, bb2, zh, zl, 0);
  dist_mfma_kernel<<<512, 512, 133120, stream>>>(cbh, cbl, zh, zl, e2, slots);
  gather_kernel<<<dim3(8, NBATCH), 256, 0, stream>>>(t2, cb, a2, bb2, slots, out, loss);
  finalize_kernel<<<1, 64, 0, stream>>>(loss, out);
}

// Round 5
// 951.494 us; speedup vs baseline: 1.5619x; 1.0275x over previous
//
#include <hip/hip_runtime.h>
#include <hip/hip_bf16.h>
#include <cstdint>

// Problem dims
#define DD 1024
#define LIN 1024
#define LP 511
#define LPAD 512
#define NBATCH 32
#define KCB 2048
#define BN_EPS 1e-5f

// Output layout (floats): q_st [32,1024,511], ids [32,511], commitment, codebook_loss
#define OUT_IDS 16744448u
#define OUT_LOSS 16760800u

// Workspace layout (float offsets). Region X = [WS_UNI, WS_AUX) is
// phase-multiplexed: phase0 conv1 operands; phase2 t2 + r/z planes + small planes.
#define WS_H1 0
#define WS_UNI 16777216
// phase0 (conv1):
#define WS_XH  (WS_UNI)                    // [2][32][512][1024] ushort (+512 f pad)
#define WS_XL  (WS_UNI + 16777728)
#define WS_WTH (WS_UNI + 33555456)         // [4][1024][1024] ushort
#define WS_WTL (WS_UNI + 35652608)
// phase2 (after conv1 done):
#define WS_T2  (WS_UNI)                    // fp32 [32][1024][512]
#define WS_RH  (WS_UNI + 16777216)         // [32][512][1024] ushort
#define WS_RL  (WS_UNI + 25165824)
#define WS_ZH  WS_RH                       // reuse after conv2 done
#define WS_ZL  WS_RL
#define WS_W2H (WS_UNI + 33554432)         // [1024][1024] ushort
#define WS_W2L (WS_UNI + 34078720)
#define WS_CBH (WS_UNI + 34603008)         // [2048][1024] ushort
#define WS_CBL (WS_UNI + 35651584)
#define WS_AUX (WS_UNI + 37749760)
#define WS_A1 (WS_AUX + 0)
#define WS_B1 (WS_AUX + 1024)
#define WS_A2 (WS_AUX + 2048)
#define WS_B2 (WS_AUX + 3072)
#define WS_E2 (WS_AUX + 4096)
#define WS_SLOTS (WS_AUX + 6144)
#define WS_LOSS (WS_AUX + 6144 + 32704)

typedef __attribute__((ext_vector_type(8))) short bf16x8;
typedef __attribute__((ext_vector_type(4))) float f32x4;
typedef __attribute__((ext_vector_type(4))) unsigned short ushort4v;
typedef __attribute__((ext_vector_type(8))) unsigned short ushort8v;

__device__ __forceinline__ void async_cp16(const void* gsrc, void* ldst) {
  __builtin_amdgcn_global_load_lds(
      (const __attribute__((address_space(1))) unsigned int*)gsrc,
      (__attribute__((address_space(3))) unsigned int*)ldst, 16, 0, 0);
}

__device__ __forceinline__ void bf16split(float v, unsigned short& hi, unsigned short& lo) {
  __hip_bfloat16 h = __float2bfloat16(v);
  float hf = __bfloat162float(h);
  __hip_bfloat16 l = __float2bfloat16(v - hf);
  hi = *(unsigned short*)&h;
  lo = *(unsigned short*)&l;
}

__device__ inline float blockReduce256(float v, float* sb) {
#pragma unroll
  for (int off = 32; off > 0; off >>= 1) v += __shfl_down(v, off);
  __syncthreads();
  if ((threadIdx.x & 63) == 0) sb[threadIdx.x >> 6] = v;
  __syncthreads();
  return sb[0] + sb[1] + sb[2] + sb[3];
}

#define VMCNT(n) asm volatile("s_waitcnt vmcnt(" #n ")" ::: "memory")

// ---------------------------------------------------------------------------
// 256x256 tile MFMA core, 512 threads = 8 waves (2M x 4N), wave tile 128x64.
// 4 planes per K=32 chunk in LDS: Ah(0), Al(8192), Bh(16384), Bl(24576)
// halfword offsets; 256 rows x 32 halfwords per plane; double-buffered
// (buffer stride 32768 halfwords = 64 KB; total 128 KB).
//
// Swizzle: 16B slot s within each 64B row stored at s ^ ((row>>1)&3).
// Applied by pre-swizzling the GLOBAL source of global_load_lds (LDS dest
// stays linear) and by the same XOR on the read side -> conflict-free
// (measured 0 SQ_LDS_BANK_CONFLICT with the 16x16 read pattern).
//
// Stage slots per wave per chunk (8 x 1KB units, issue order = consumption
// order): 0:Bh rows 16w, 1:Bh 128+16w, 2:Bl 16w, 3:Bl 128+16w, 4..7: A phase
// p=slot-4 unit (plane by w&1, half by (w>>1)&1, j by w>>2). Next-chunk
// phase-0 needs slots 0..4; phase p needs slot 4+p.  Steady-state waits:
// phase p entry -> vmcnt(3+p) (issued 8+2p, oldest 5+p done). Last chunk
// (no prefetch): vmcnt(3-p).
//
// MFMA issue order is TERM-MAJOR so same-accumulator reuse is spaced 8
// MFMAs apart (dependency distance 1 -> 8; was the 63% MfmaUtil limiter).
template <typename SF>
__device__ __forceinline__ void stage_slot(const SF& sf, int c, int slot,
                                           unsigned short* smbase, int wid,
                                           int lane) {
  int plane, r0;
  if (slot < 4) {
    plane = 2 + (slot >> 1);
    r0 = ((slot & 1) << 7) + (wid << 4);
  } else {
    plane = wid & 1;
    r0 = (((wid >> 1) & 1) << 7) + ((slot - 4) << 5) + ((wid >> 2) << 4);
  }
  const unsigned short* g = sf(c, plane) + (size_t)(r0 + (lane >> 2)) * 1024 +
                            (((lane & 3) ^ ((lane >> 3) & 3)) << 3);
  unsigned short* d = smbase + plane * 8192 + r0 * 32;  // HW adds lane*16B
  async_cp16(g, d);
}

template <typename SF>
__device__ __forceinline__ void mfma256_core(const SF& sf, unsigned short* sm,
                                             int nkc, f32x4 (&acc)[8][4]) {
  const int tid = threadIdx.x;
  const int wid = tid >> 6, lane = tid & 63;
  const int wm = wid >> 2, wn = wid & 3;
  // swizzled 16B-slot halfword offset; sigma = ((row>>1)&3) = ((lane>>1)&3)
  // since all fragment row-bases are multiples of 16.
  const int slot16 = (((lane >> 4) ^ ((lane >> 1) & 3)) << 3);
  const int arow = (wm << 7) + (lane & 15);
  const int brow = (wn << 6) + (lane & 15);

  // prologue: chunk 0's 8 slots in order
#pragma unroll
  for (int s = 0; s < 8; ++s) stage_slot(sf, 0, s, sm, wid, lane);

  bf16x8 fbh[4], fbl[4];
  for (int c = 0; c < nkc; ++c) {
    unsigned short* buf = sm + ((c & 1) << 15);
    unsigned short* nbuf = sm + (((c + 1) & 1) << 15);
    const unsigned short* As = buf;
    const unsigned short* Als = buf + 8192;
    const unsigned short* Bs = buf + 16384;
    const unsigned short* Bls = buf + 24576;
    const bool pre = (c + 1 < nkc);
#pragma unroll
    for (int p = 0; p < 4; ++p) {
      if (pre) {
        if (p == 0) { VMCNT(3); } else if (p == 1) { VMCNT(4); }
        else if (p == 2) { VMCNT(5); } else { VMCNT(6); }
      } else {
        if (p == 0) { VMCNT(3); } else if (p == 1) { VMCNT(2); }
        else if (p == 2) { VMCNT(1); } else { VMCNT(0); }
      }
      __builtin_amdgcn_s_barrier();
      asm volatile("" ::: "memory");
      __builtin_amdgcn_sched_barrier(0);
      if (p == 0) {
#pragma unroll
        for (int nt = 0; nt < 4; ++nt) {
          int r = brow + nt * 16;
          fbh[nt] = *(const bf16x8*)(Bs + r * 32 + slot16);
          fbl[nt] = *(const bf16x8*)(Bls + r * 32 + slot16);
        }
      }
      bf16x8 fah0, fal0, fah1, fal1;
      {
        int r0 = arow + ((2 * p) << 4);
        int r1 = r0 + 16;
        fah0 = *(const bf16x8*)(As + r0 * 32 + slot16);
        fal0 = *(const bf16x8*)(Als + r0 * 32 + slot16);
        fah1 = *(const bf16x8*)(As + r1 * 32 + slot16);
        fal1 = *(const bf16x8*)(Als + r1 * 32 + slot16);
      }
      if (pre) {
        stage_slot(sf, c + 1, 2 * p + 0, nbuf, wid, lane);
        stage_slot(sf, c + 1, 2 * p + 1, nbuf, wid, lane);
      }
      __builtin_amdgcn_s_setprio(1);
      // term-major: hh(both halves) -> h*bl -> l*bh; same-acc spacing 8
#pragma unroll
      for (int nt = 0; nt < 4; ++nt)
        acc[2 * p][nt] = __builtin_amdgcn_mfma_f32_16x16x32_bf16(fah0, fbh[nt], acc[2 * p][nt], 0, 0, 0);
#pragma unroll
      for (int nt = 0; nt < 4; ++nt)
        acc[2 * p + 1][nt] = __builtin_amdgcn_mfma_f32_16x16x32_bf16(fah1, fbh[nt], acc[2 * p + 1][nt], 0, 0, 0);
#pragma unroll
      for (int nt = 0; nt < 4; ++nt)
        acc[2 * p][nt] = __builtin_amdgcn_mfma_f32_16x16x32_bf16(fah0, fbl[nt], acc[2 * p][nt], 0, 0, 0);
#pragma unroll
      for (int nt = 0; nt < 4; ++nt)
        acc[2 * p + 1][nt] = __builtin_amdgcn_mfma_f32_16x16x32_bf16(fah1, fbl[nt], acc[2 * p + 1][nt], 0, 0, 0);
#pragma unroll
      for (int nt = 0; nt < 4; ++nt)
        acc[2 * p][nt] = __builtin_amdgcn_mfma_f32_16x16x32_bf16(fal0, fbh[nt], acc[2 * p][nt], 0, 0, 0);
#pragma unroll
      for (int nt = 0; nt < 4; ++nt)
        acc[2 * p + 1][nt] = __builtin_amdgcn_mfma_f32_16x16x32_bf16(fal1, fbh[nt], acc[2 * p + 1][nt], 0, 0, 0);
      __builtin_amdgcn_s_setprio(0);
    }
  }
}

// ---------------------------------------------------------------------------
// split w1 [o][i][t] fp32 -> wth/wtl [t][o][i] bf16 hi/lo
__global__ __launch_bounds__(256) void split_w1_kernel(
    const float* __restrict__ w, unsigned short* __restrict__ wth,
    unsigned short* __restrict__ wtl) {
  int idx = blockIdx.x * 256 + threadIdx.x;
  int o = idx >> 10, i = idx & 1023;
  float4 v = *(const float4*)&w[(size_t)idx * 4];
  float vv[4] = {v.x, v.y, v.z, v.w};
#pragma unroll
  for (int t = 0; t < 4; ++t) {
    unsigned short hi, lo;
    bf16split(vv[t], hi, lo);
    size_t off = (((size_t)(t << 10) + o) << 10) + i;
    wth[off] = hi;
    wtl[off] = lo;
  }
}

// ---------------------------------------------------------------------------
// generic row-major split: src [rows][1024] fp32 -> dsth/dstl bf16 hi/lo
__global__ __launch_bounds__(256) void split_rows_kernel(
    const float* __restrict__ src, unsigned short* __restrict__ dsth,
    unsigned short* __restrict__ dstl) {
  size_t base = ((size_t)blockIdx.x * 256 + threadIdx.x) * 4;
  float4 v = *(const float4*)&src[base];
  float vv[4] = {v.x, v.y, v.z, v.w};
  ushort4v h, l;
#pragma unroll
  for (int j = 0; j < 4; ++j) {
    unsigned short hi, lo;
    bf16split(vv[j], hi, lo);
    h[j] = hi;
    l[j] = lo;
  }
  *(ushort4v*)&dsth[base] = h;
  *(ushort4v*)&dstl[base] = l;
}

// ---------------------------------------------------------------------------
// split/transpose x [n][i][l] fp32 -> xh/xl [P][n][l>>1][i] bf16 (P = l&1)
// Consumer side vectorized: each lane emits 8 consecutive channels -> 16B
// ushort8 stores per plane.
__global__ __launch_bounds__(256) void split_x_kernel(
    const float* __restrict__ x, unsigned short* __restrict__ xh,
    unsigned short* __restrict__ xl) {
  __shared__ float lsT[128 * 65];
  const int l0 = blockIdx.x * 128;
  const int i0 = blockIdx.y * 64;
  const int nB = blockIdx.z;
  const int tid = threadIdx.x;
#pragma unroll
  for (int p = 0; p < 8; ++p) {
    int flat = p * 256 + tid;
    int row = flat >> 5, col4 = (flat & 31) * 4;
    float4 v = *(const float4*)&x[((size_t)nB * DD + i0 + row) * LIN + l0 + col4];
    lsT[(col4 + 0) * 65 + row] = v.x;
    lsT[(col4 + 1) * 65 + row] = v.y;
    lsT[(col4 + 2) * 65 + row] = v.z;
    lsT[(col4 + 3) * 65 + row] = v.w;
  }
  __syncthreads();
  const int lo2 = (l0 >> 1);
  const int ilg = (tid & 7) * 8;   // 8-channel group
  const int q = tid >> 3;          // 0..31
#pragma unroll
  for (int p = 0; p < 4; ++p) {
    const int idx = p * 32 + q;    // l-column 0..127
    const int par = idx & 1, cp = idx >> 1;
    ushort8v hv, lv;
#pragma unroll
    for (int j = 0; j < 8; ++j) {
      unsigned short hi, lo;
      bf16split(lsT[idx * 65 + ilg + j], hi, lo);
      hv[j] = hi;
      lv[j] = lo;
    }
    size_t d = (((size_t)(par * 32 + nB) * 512) + lo2 + cp) * 1024 + i0 + ilg;
    *(ushort8v*)&xh[d] = hv;
    *(ushort8v*)&xl[d] = lv;
  }
}

// ---------------------------------------------------------------------------
// transpose + per-channel affine (+optional relu) + bf16 split:
// src [n][c][LPAD] fp32 -> dsth/dstl [n][LPAD][1024] bf16 hi/lo of (a*v+b)
// Consumer side vectorized: 16B ushort8 stores per plane.
__global__ __launch_bounds__(256) void trans_affine_split_kernel(
    const float* __restrict__ src, const float* __restrict__ a,
    const float* __restrict__ b, unsigned short* __restrict__ dsth,
    unsigned short* __restrict__ dstl, int do_relu) {
  __shared__ float lsT[128 * 65];
  const int l0 = blockIdx.x * 128;
  const int i0 = blockIdx.y * 64;
  const int nB = blockIdx.z;
  const int tid = threadIdx.x;
#pragma unroll
  for (int p = 0; p < 8; ++p) {
    int flat = p * 256 + tid;
    int row = flat >> 5, col4 = (flat & 31) * 4;
    float4 v = *(const float4*)&src[((size_t)nB * DD + i0 + row) * LPAD + l0 + col4];
    lsT[(col4 + 0) * 65 + row] = v.x;
    lsT[(col4 + 1) * 65 + row] = v.y;
    lsT[(col4 + 2) * 65 + row] = v.z;
    lsT[(col4 + 3) * 65 + row] = v.w;
  }
  __syncthreads();
  const int ilg = (tid & 7) * 8;
  const int q = tid >> 3;  // 0..31
  float4 a0 = *(const float4*)&a[i0 + ilg];
  float4 a1 = *(const float4*)&a[i0 + ilg + 4];
  float4 b0 = *(const float4*)&b[i0 + ilg];
  float4 b1 = *(const float4*)&b[i0 + ilg + 4];
  float ac[8] = {a0.x, a0.y, a0.z, a0.w, a1.x, a1.y, a1.z, a1.w};
  float bc[8] = {b0.x, b0.y, b0.z, b0.w, b1.x, b1.y, b1.z, b1.w};
#pragma unroll
  for (int p = 0; p < 4; ++p) {
    const int cp = p * 32 + q;
    ushort8v hv, lv;
#pragma unroll
    for (int j = 0; j < 8; ++j) {
      float v = fmaf(ac[j], lsT[cp * 65 + ilg + j], bc[j]);
      if (do_relu) v = fmaxf(v, 0.f);
      unsigned short hi, lo;
      bf16split(v, hi, lo);
      hv[j] = hi;
      lv[j] = lo;
    }
    size_t d = (((size_t)nB * 512) + l0 + cp) * 1024 + i0 + ilg;
    *(ushort8v*)&dsth[d] = hv;
    *(ushort8v*)&dstl[d] = lv;
  }
}

// ---------------------------------------------------------------------------
// conv1 as MFMA GEMM (3-term bf16 split), h1[n][o][l'] += bias. 256x256 tile.
// 1-D grid, XCD-aware decode: lin%8 = x + 2*(n&3) so the 4 o-tiles sharing an
// x-slice co-reside on one XCD (x-slice L2-resident, fetched once).
__global__ __launch_bounds__(512, 2) void conv1_mfma_kernel(
    const unsigned short* __restrict__ wth, const unsigned short* __restrict__ wtl,
    const unsigned short* __restrict__ xh, const unsigned short* __restrict__ xl,
    const float* __restrict__ bias, float* __restrict__ h1) {
  extern __shared__ unsigned short sm[];
  const int tid = threadIdx.x;
  const int wid = tid >> 6, lane = tid & 63;
  const int lin = blockIdx.x;
  const int lb = (lin & 1) * 256;
  const int nB = ((lin >> 1) & 3) | ((lin >> 5) << 2);
  const int ob = ((lin >> 3) & 3) * 256;

  f32x4 acc[8][4];
#pragma unroll
  for (int a = 0; a < 8; ++a)
#pragma unroll
    for (int b = 0; b < 4; ++b) acc[a][b] = (f32x4){0.f, 0.f, 0.f, 0.f};

  auto sf = [&](int c, int plane) -> const unsigned short* {
    int t = c >> 5, kc = c & 31;
    if (plane == 0) return wth + ((((size_t)t << 10) + ob) << 10) + kc * 32;
    if (plane == 1) return wtl + ((((size_t)t << 10) + ob) << 10) + kc * 32;
    const unsigned short* xp = (plane == 2) ? xh : xl;
    return xp + ((((size_t)((t & 1) * 32 + nB) * 512) + lb + (t >> 1)) << 10) + kc * 32;
  };
  mfma256_core(sf, sm, 128, acc);

  const int wm = wid >> 2, wn = wid & 3;
#pragma unroll
  for (int mt = 0; mt < 8; ++mt) {
    const int o_base = ob + (wm << 7) + mt * 16 + ((lane >> 4) << 2);
#pragma unroll
    for (int nt = 0; nt < 4; ++nt) {
      const int l = lb + (wn << 6) + nt * 16 + (lane & 15);
      if (l < LP) {
#pragma unroll
        for (int rg = 0; rg < 4; ++rg)
          h1[((size_t)(nB << 10) + o_base + rg) * LPAD + l] =
              acc[mt][nt][rg] + bias[o_base + rg];
      }
    }
  }
}

// ---------------------------------------------------------------------------
// conv2 as MFMA GEMM: t2 = h1 + W2 @ r + b2c   (r = pre-split relu(a1*h1+b1))
__global__ __launch_bounds__(512, 2) void conv2_mfma_kernel(
    const unsigned short* __restrict__ w2h, const unsigned short* __restrict__ w2l,
    const unsigned short* __restrict__ rh, const unsigned short* __restrict__ rl,
    const float* __restrict__ b2c, const float* __restrict__ h1,
    float* __restrict__ t2) {
  extern __shared__ unsigned short sm[];
  const int tid = threadIdx.x;
  const int wid = tid >> 6, lane = tid & 63;
  const int lin = blockIdx.x;
  const int lb = (lin & 1) * 256;
  const int nB = ((lin >> 1) & 3) | ((lin >> 5) << 2);
  const int ob = ((lin >> 3) & 3) * 256;

  f32x4 acc[8][4];
#pragma unroll
  for (int a = 0; a < 8; ++a)
#pragma unroll
    for (int b = 0; b < 4; ++b) acc[a][b] = (f32x4){0.f, 0.f, 0.f, 0.f};

  auto sf = [&](int c, int plane) -> const unsigned short* {
    if (plane == 0) return w2h + ((size_t)ob << 10) + (size_t)c * 32;
    if (plane == 1) return w2l + ((size_t)ob << 10) + (size_t)c * 32;
    const unsigned short* rp = (plane == 2) ? rh : rl;
    return rp + (((size_t)nB * 512 + lb) << 10) + (size_t)c * 32;
  };
  mfma256_core(sf, sm, 32, acc);

  const int wm = wid >> 2, wn = wid & 3;
#pragma unroll
  for (int mt = 0; mt < 8; ++mt) {
    const int o_base = ob + (wm << 7) + mt * 16 + ((lane >> 4) << 2);
#pragma unroll
    for (int nt = 0; nt < 4; ++nt) {
      const int l = lb + (wn << 6) + nt * 16 + (lane & 15);
      if (l < LP) {
#pragma unroll
        for (int rg = 0; rg < 4; ++rg) {
          size_t off = ((size_t)(nB << 10) + o_base + rg) * LPAD + l;
          t2[off] = h1[off] + acc[mt][nt][rg] + b2c[o_base + rg];
        }
      }
    }
  }
}

// ---------------------------------------------------------------------------
// dist as MFMA GEMM: S = cb @ z; argmin_k (e2[k] - 2S) via packed u64 atomicMin
// 1-D grid, XCD decode: lin%8 = l-tile + 2*(n&3).
__global__ __launch_bounds__(512, 2) void dist_mfma_kernel(
    const unsigned short* __restrict__ cbh, const unsigned short* __restrict__ cbl,
    const unsigned short* __restrict__ zh, const unsigned short* __restrict__ zl,
    const float* __restrict__ e2, unsigned long long* __restrict__ slots) {
  extern __shared__ unsigned short sm[];
  unsigned long long* best = (unsigned long long*)(sm + 65536);
  const int tid = threadIdx.x;
  const int wid = tid >> 6, lane = tid & 63;
  const int lin = blockIdx.x;
  const int lb = (lin & 1) * 256;
  const int nB = ((lin >> 1) & 3) | ((lin >> 6) << 2);
  const int kb = ((lin >> 3) & 7) * 256;

  if (tid < 256) best[tid] = ~0ULL;

  f32x4 acc[8][4];
#pragma unroll
  for (int a = 0; a < 8; ++a)
#pragma unroll
    for (int b = 0; b < 4; ++b) acc[a][b] = (f32x4){0.f, 0.f, 0.f, 0.f};

  auto sf = [&](int c, int plane) -> const unsigned short* {
    if (plane == 0) return cbh + ((size_t)kb << 10) + (size_t)c * 32;
    if (plane == 1) return cbl + ((size_t)kb << 10) + (size_t)c * 32;
    const unsigned short* zp = (plane == 2) ? zh : zl;
    return zp + (((size_t)nB * 512 + lb) << 10) + (size_t)c * 32;
  };
  mfma256_core(sf, sm, 32, acc);

  const int wm = wid >> 2, wn = wid & 3;
#pragma unroll
  for (int nt = 0; nt < 4; ++nt) {
    const int col = (wn << 6) + nt * 16 + (lane & 15);
    float dmin = 3.4e38f;
    int kmin = 0;
#pragma unroll
    for (int mt = 0; mt < 8; ++mt) {
      const int kbase = kb + (wm << 7) + mt * 16 + ((lane >> 4) << 2);
#pragma unroll
      for (int rg = 0; rg < 4; ++rg) {
        float dist = fmaf(-2.f, acc[mt][nt][rg], e2[kbase + rg]);
        if (dist < dmin) { dmin = dist; kmin = kbase + rg; }
      }
    }
    unsigned long long pk =
        ((unsigned long long)__float_as_uint(dmin) << 32) | (unsigned)kmin;
    atomicMin(&best[col], pk);
  }
  __syncthreads();
  if (tid < 256) {
    int l = lb + tid;
    if (l < LP) atomicMin(&slots[(size_t)nB * LP + l], best[tid]);
  }
}

// ---------------------------------------------------------------------------
__global__ __launch_bounds__(256) void bn_stats_kernel(
    const float* __restrict__ src, const float* __restrict__ gamma,
    const float* __restrict__ beta, float* __restrict__ a_out,
    float* __restrict__ b_out) {
  __shared__ float sb[4];
  const int c = blockIdx.x;
  const float* p = src + (size_t)c * LPAD;
  float s1 = 0.f, s2 = 0.f;
  for (int idx = threadIdx.x; idx < NBATCH * LP; idx += 256) {
    int nn = idx / LP;
    int l = idx - nn * LP;
    float v = p[(size_t)nn * DD * LPAD + l];
    s1 += v;
    s2 = fmaf(v, v, s2);
  }
  s1 = blockReduce256(s1, sb);
  s2 = blockReduce256(s2, sb);
  if (threadIdx.x == 0) {
    const float inv = 1.f / (float)(NBATCH * LP);
    float m = s1 * inv;
    float var = fmaf(-m, m, s2 * inv);
    float a = gamma[c] * rsqrtf(var + BN_EPS);
    a_out[c] = a;
    b_out[c] = fmaf(-m, a, beta[c]);
  }
}

// ---------------------------------------------------------------------------
__global__ __launch_bounds__(256) void e2_kernel(const float* __restrict__ cb,
                                                 float* __restrict__ e2) {
  __shared__ float sb[4];
  const int k = blockIdx.x;
  float s = 0.f;
  for (int d = threadIdx.x; d < DD; d += 256) {
    float v = cb[(size_t)k * DD + d];
    s = fmaf(v, v, s);
  }
  s = blockReduce256(s, sb);
  if (threadIdx.x == 0) e2[k] = s;
}

// ---------------------------------------------------------------------------
// gather: codebook rows via float4 (4 consecutive d per thread) to cut the
// scattered-load transaction count 4x; a2/b2 as wave-uniform float4.
__global__ __launch_bounds__(256) void gather_kernel(
    const float* __restrict__ t2, const float* __restrict__ cb,
    const float* __restrict__ a2, const float* __restrict__ b2,
    const unsigned long long* __restrict__ slots, float* __restrict__ out,
    float* __restrict__ loss_acc) {
  __shared__ int ks[64];
  __shared__ float sb[4];
  const int l0 = blockIdx.x * 64;
  const int n = blockIdx.y;
  const int tid = threadIdx.x, tx = tid & 63, ty = tid >> 6;
  if (tid < 64) {
    int l = l0 + tid;
    int k = 0;
    if (l < LP) {
      k = (int)(unsigned)(slots[(size_t)n * LP + l] & 0xffffffffULL);
      out[OUT_IDS + (size_t)n * LP + l] = (float)k;
    }
    ks[tid] = k;
  }
  __syncthreads();
  const int l = l0 + tx;
  const bool valid = (l < LP);
  const int k = ks[tx];
  const float* cbk = cb + (size_t)k * DD;
  const float* tn = t2 + (size_t)n * DD * LPAD;
  float* qo = out + (size_t)n * DD * LP;
  float lsum = 0.f;
  for (int d0 = 0; d0 < DD; d0 += 16) {
    const int d = d0 + ty * 4;
    float4 q4 = *(const float4*)&cbk[d];
    float qa[4] = {q4.x, q4.y, q4.z, q4.w};
    float4 a4 = *(const float4*)&a2[d];
    float4 b4 = *(const float4*)&b2[d];
    float aa[4] = {a4.x, a4.y, a4.z, a4.w};
    float ba[4] = {b4.x, b4.y, b4.z, b4.w};
    if (valid) {
#pragma unroll
      for (int j = 0; j < 4; ++j) {
        float z = fmaf(aa[j], tn[(size_t)(d + j) * LPAD + l], ba[j]);
        qo[(size_t)(d + j) * LP + l] = qa[j];
        float e = z - qa[j];
        lsum = fmaf(e, e, lsum);
      }
    }
  }
  lsum = blockReduce256(lsum, sb);
  if (tid == 0) atomicAdd(loss_acc, lsum);
}

__global__ void finalize_kernel(const float* __restrict__ loss_acc,
                                float* __restrict__ out) {
  if (threadIdx.x == 0) {
    float m = loss_acc[0] * (1.f / 16744448.f);
    out[OUT_LOSS] = m;
    out[OUT_LOSS + 1] = m;
  }
}

// ---------------------------------------------------------------------------
extern "C" void kernel_launch(void* const* d_in, const int* in_sizes, int n_in,
                              void* d_out, int out_size, void* d_ws,
                              size_t ws_size, hipStream_t stream) {
  const float* x = (const float*)d_in[0];
  const float* w1 = (const float*)d_in[1];
  const float* b1c = (const float*)d_in[2];
  const float* g1 = (const float*)d_in[3];
  const float* be1 = (const float*)d_in[4];
  const float* w2 = (const float*)d_in[5];
  const float* b2c = (const float*)d_in[6];
  const float* g2 = (const float*)d_in[7];
  const float* be2 = (const float*)d_in[8];
  const float* cb = (const float*)d_in[9];
  float* out = (float*)d_out;
  float* ws = (float*)d_ws;

  float* h1 = ws + WS_H1;
  float* t2 = ws + WS_T2;
  unsigned short* xh = (unsigned short*)(ws + WS_XH);
  unsigned short* xl = (unsigned short*)(ws + WS_XL);
  unsigned short* wth = (unsigned short*)(ws + WS_WTH);
  unsigned short* wtl = (unsigned short*)(ws + WS_WTL);
  unsigned short* rh = (unsigned short*)(ws + WS_RH);
  unsigned short* rl = (unsigned short*)(ws + WS_RL);
  unsigned short* zh = (unsigned short*)(ws + WS_ZH);
  unsigned short* zl = (unsigned short*)(ws + WS_ZL);
  unsigned short* w2h = (unsigned short*)(ws + WS_W2H);
  unsigned short* w2l = (unsigned short*)(ws + WS_W2L);
  unsigned short* cbh = (unsigned short*)(ws + WS_CBH);
  unsigned short* cbl = (unsigned short*)(ws + WS_CBL);
  float* a1 = ws + WS_A1;
  float* bb1 = ws + WS_B1;
  float* a2 = ws + WS_A2;
  float* bb2 = ws + WS_B2;
  float* e2 = ws + WS_E2;
  unsigned long long* slots = (unsigned long long*)(ws + WS_SLOTS);
  float* loss = ws + WS_LOSS;

  static int attr_done = 0;
  if (!attr_done) {
    (void)hipFuncSetAttribute(reinterpret_cast<const void*>(conv1_mfma_kernel),
                              hipFuncAttributeMaxDynamicSharedMemorySize, 135168);
    (void)hipFuncSetAttribute(reinterpret_cast<const void*>(conv2_mfma_kernel),
                              hipFuncAttributeMaxDynamicSharedMemorySize, 135168);
    (void)hipFuncSetAttribute(reinterpret_cast<const void*>(dist_mfma_kernel),
                              hipFuncAttributeMaxDynamicSharedMemorySize, 135168);
    attr_done = 1;
  }

  (void)hipMemsetAsync(slots, 0xFF,
                       (size_t)NBATCH * LP * sizeof(unsigned long long), stream);
  (void)hipMemsetAsync(loss, 0, sizeof(float), stream);

  // phase 0: conv1 operand prep + conv1
  split_w1_kernel<<<4096, 256, 0, stream>>>(w1, wth, wtl);
  split_x_kernel<<<dim3(8, 16, NBATCH), 256, 0, stream>>>(x, xh, xl);
  conv1_mfma_kernel<<<256, 512, 131072, stream>>>(wth, wtl, xh, xl, b1c, h1);
  // phase 1: BN1 stats, then conv2 operand prep (overlays dead conv1 planes)
  bn_stats_kernel<<<DD, 256, 0, stream>>>(h1, g1, be1, a1, bb1);
  split_rows_kernel<<<1024, 256, 0, stream>>>(w2, w2h, w2l);
  split_rows_kernel<<<2048, 256, 0, stream>>>(cb, cbh, cbl);
  e2_kernel<<<KCB, 256, 0, stream>>>(cb, e2);
  trans_affine_split_kernel<<<dim3(4, 16, NBATCH), 256, 0, stream>>>(
      h1, a1, bb1, rh, rl, 1);
  conv2_mfma_kernel<<<256, 512, 131072, stream>>>(w2h, w2l, rh, rl, b2c, h1, t2);
  // phase 2: BN2 stats, z prep (overlays dead r planes), dist, gather
  bn_stats_kernel<<<DD, 256, 0, stream>>>(t2, g2, be2, a2, bb2);
  trans_affine_split_kernel<<<dim3(4, 16, NBATCH), 256, 0, stream>>>(
      t2, a2, bb2, zh, zl, 0);
  dist_mfma_kernel<<<512, 512, 133120, stream>>>(cbh, cbl, zh, zl, e2, slots);
  gather_kernel<<<dim3(8, NBATCH), 256, 0, stream>>>(t2, cb, a2, bb2, slots, out, loss);
  finalize_kernel<<<1, 64, 0, stream>>>(loss, out);
}